// Round 8
// baseline (732.112 us; speedup 1.0000x reference)
//
#include <hip/hip_runtime.h>
#include <math.h>

#define HIDDEN 64
#define LATENT 32
#define HEADS 4
#define IN_DIM 128
#define NUM_CLASSES 10
#define NUM_GRAPHS 64
#define NEG_SLOPE 0.2f
#define HC 256  // HEADS*HIDDEN

// ---------------- utility ----------------
__global__ void k_easum(const float* __restrict__ ea, int E, float* __restrict__ ea_sum) {
    float s0 = 0.f, s1 = 0.f, s2 = 0.f;
    for (int e = blockIdx.x * blockDim.x + threadIdx.x; e < E; e += gridDim.x * blockDim.x) {
        s0 += ea[e * 3 + 0];
        s1 += ea[e * 3 + 1];
        s2 += ea[e * 3 + 2];
    }
    for (int off = 32; off; off >>= 1) {
        s0 += __shfl_xor(s0, off);
        s1 += __shfl_xor(s1, off);
        s2 += __shfl_xor(s2, off);
    }
    if ((threadIdx.x & 63) == 0) {
        atomicAdd(&ea_sum[0], s0);
        atomicAdd(&ea_sum[1], s1);
        atomicAdd(&ea_sum[2], s2);
    }
}

// ---------------- CSR build ----------------
__global__ void k_hist(const int* __restrict__ ei, int* __restrict__ deg, int E0) {
    int e = blockIdx.x * blockDim.x + threadIdx.x;
    if (e < E0) atomicAdd(&deg[ei[E0 + e]], 1);
}

__global__ void k_scan1(const int* __restrict__ deg, int* __restrict__ off,
                        int* __restrict__ bsum, int N) {
    __shared__ int sh[256];
    int t = threadIdx.x, i = blockIdx.x * 256 + t;
    int v = (i < N) ? deg[i] : 0;
    sh[t] = v;
    __syncthreads();
    for (int d = 1; d < 256; d <<= 1) {
        int x = (t >= d) ? sh[t - d] : 0;
        __syncthreads();
        sh[t] += x;
        __syncthreads();
    }
    if (i < N) off[i] = sh[t] - v;  // exclusive
    if (t == 255) bsum[blockIdx.x] = sh[255];
}

__global__ void k_scan2(int* __restrict__ bsum, int nb) {
    __shared__ int sh[256];
    int t = threadIdx.x;
    int v = (t < nb) ? bsum[t] : 0;
    sh[t] = v;
    __syncthreads();
    for (int d = 1; d < 256; d <<= 1) {
        int x = (t >= d) ? sh[t - d] : 0;
        __syncthreads();
        sh[t] += x;
        __syncthreads();
    }
    if (t < nb) bsum[t] = sh[t] - v;  // exclusive block offsets
}

__global__ void k_scan3(int* __restrict__ off, const int* __restrict__ bsum,
                        int* __restrict__ cur, int N) {
    int i = blockIdx.x * 256 + threadIdx.x;
    if (i >= N) return;
    int o = off[i] + bsum[blockIdx.x];
    off[i] = o;
    cur[i] = o;
}

__global__ void k_scatter(const int* __restrict__ ei, const float* __restrict__ ea,
                          int* __restrict__ cur, int* __restrict__ csr_src,
                          float4* __restrict__ csr_a, int E0) {
    int e = blockIdx.x * blockDim.x + threadIdx.x;
    if (e >= E0) return;
    int dst = ei[E0 + e];
    int pos = atomicAdd(&cur[dst], 1);
    csr_src[pos] = ei[e];
    csr_a[pos] = make_float4(ea[e * 3], ea[e * 3 + 1], ea[e * 3 + 2], 0.f);
}

// ---------------- fused dual GEMM: xl = X@Wl, xr = X@Wr in ONE dispatch ----------------
// High-occupancy outer-product form. X values are WAVE-UNIFORM (address depends only on
// blockIdx + loop constants) -> compiler promotes them to s_load on the scalar pipe
// (free vs VALU). No LDS, no barriers. Per k: 2 coalesced VMEM (W) + 16 scalar loads
// + 32 FMAs. Each thread owns column t of both xl and xr for 16 nodes.
template <int K>
__global__ void k_gemm(const float* __restrict__ X, const float* __restrict__ Wl,
                       const float* __restrict__ Wr, float* __restrict__ xl,
                       float* __restrict__ xr, int N) {
    constexpr int NPB = 16;
    const int t = threadIdx.x;
    const int M0 = blockIdx.x * NPB;

    // uniform clamped row bases (no divergence; protects OOB reads on tail blocks)
    const float* Xrow[NPB];
#pragma unroll
    for (int n = 0; n < NPB; n++) {
        int gn = M0 + n;
        if (gn >= N) gn = N - 1;
        Xrow[n] = X + (size_t)gn * K;
    }

    float accl[NPB], accr[NPB];
#pragma unroll
    for (int n = 0; n < NPB; n++) { accl[n] = 0.f; accr[n] = 0.f; }

    const float* wlp = Wl + t;
    const float* wrp = Wr + t;
#pragma unroll 4
    for (int k = 0; k < K; k++) {
        float wl = wlp[(size_t)k * HC];
        float wr = wrp[(size_t)k * HC];
#pragma unroll
        for (int n = 0; n < NPB; n++) {
            float a = Xrow[n][k];  // uniform -> scalar load
            accl[n] += a * wl;
            accr[n] += a * wr;
        }
    }

#pragma unroll
    for (int n = 0; n < NPB; n++) {
        int gn = M0 + n;
        if (gn < N) {
            xl[(size_t)gn * HC + t] = accl[n];
            xr[(size_t)gn * HC + t] = accr[n];
        }
    }
}

// ---------------- fused GATv2 layer: wave per node, online softmax ----------------
// lane L holds cols 4L..4L+3 of the 256-wide row; head h = L>>4
__global__ void k_gat(const float* __restrict__ xl, const float* __restrict__ xr,
                      const int* __restrict__ csr_src, const float4* __restrict__ csr_a,
                      const int* __restrict__ off, const int* __restrict__ deg,
                      const float* __restrict__ easum, float invE,
                      const float* __restrict__ We, const float* __restrict__ att,
                      const float* __restrict__ bias, float* __restrict__ out, int N) {
    int wid = (blockIdx.x * blockDim.x + threadIdx.x) >> 6;
    int L = threadIdx.x & 63;
    if (wid >= N) return;
    int n = wid;

    float4 xr4 = ((const float4*)(xr + (size_t)n * HC))[L];
    float4 w0 = ((const float4*)We)[L];
    float4 w1 = ((const float4*)(We + HC))[L];
    float4 w2 = ((const float4*)(We + 2 * HC))[L];
    float4 at = ((const float4*)att)[L];

    float m = -INFINITY, d = 0.f;
    float acc0 = 0.f, acc1 = 0.f, acc2 = 0.f, acc3 = 0.f;
    int base = off[n], cnt = deg[n];

    for (int i = -1; i < cnt; i++) {
        int src;
        float a0, a1, a2;
        if (i < 0) {  // self loop, mean edge attr
            src = n;
            a0 = easum[0] * invE;
            a1 = easum[1] * invE;
            a2 = easum[2] * invE;
        } else {
            src = csr_src[base + i];
            float4 a = csr_a[base + i];
            a0 = a.x; a1 = a.y; a2 = a.z;
        }
        float4 xs = ((const float4*)(xl + (size_t)src * HC))[L];
        float s0 = xs.x + xr4.x + (a0 * w0.x + a1 * w1.x + a2 * w2.x);
        float s1 = xs.y + xr4.y + (a0 * w0.y + a1 * w1.y + a2 * w2.y);
        float s2 = xs.z + xr4.z + (a0 * w0.z + a1 * w1.z + a2 * w2.z);
        float s3 = xs.w + xr4.w + (a0 * w0.w + a1 * w1.w + a2 * w2.w);
        s0 = (s0 > 0.f) ? s0 : NEG_SLOPE * s0;
        s1 = (s1 > 0.f) ? s1 : NEG_SLOPE * s1;
        s2 = (s2 > 0.f) ? s2 : NEG_SLOPE * s2;
        s3 = (s3 > 0.f) ? s3 : NEG_SLOPE * s3;
        float p = s0 * at.x + s1 * at.y + s2 * at.z + s3 * at.w;
        // segmented butterfly over the 16 lanes of this head
        p += __shfl_xor(p, 1);
        p += __shfl_xor(p, 2);
        p += __shfl_xor(p, 4);
        p += __shfl_xor(p, 8);
        // online softmax update
        float mn = fmaxf(m, p);
        float sc = __expf(m - mn);
        float ex = __expf(p - mn);
        d = d * sc + ex;
        acc0 = acc0 * sc + ex * xs.x;
        acc1 = acc1 * sc + ex * xs.y;
        acc2 = acc2 * sc + ex * xs.z;
        acc3 = acc3 * sc + ex * xs.w;
        m = mn;
    }
    float inv_d = 1.f / d;
    float v0 = acc0 * inv_d, v1 = acc1 * inv_d, v2 = acc2 * inv_d, v3 = acc3 * inv_d;
    // head-mean: sum over lanes L^16, L^32
    v0 += __shfl_xor(v0, 16); v1 += __shfl_xor(v1, 16);
    v2 += __shfl_xor(v2, 16); v3 += __shfl_xor(v3, 16);
    v0 += __shfl_xor(v0, 32); v1 += __shfl_xor(v1, 32);
    v2 += __shfl_xor(v2, 32); v3 += __shfl_xor(v3, 32);
    if (L < 16) {
        float4 bx = ((const float4*)bias)[L];
        float4 o;
        o.x = fmaxf(0.25f * v0 + bx.x, 0.f);
        o.y = fmaxf(0.25f * v1 + bx.y, 0.f);
        o.z = fmaxf(0.25f * v2 + bx.z, 0.f);
        o.w = fmaxf(0.25f * v3 + bx.w, 0.f);
        ((float4*)(out + (size_t)n * HIDDEN))[L] = o;
    }
}

// ---------------- z = h @ W_mu + b_mu  (64 -> 32) ----------------
__global__ void k_mu(const float* __restrict__ h, const float* __restrict__ Wmu,
                     const float* __restrict__ bmu, float* __restrict__ z, int N) {
    int i = blockIdx.x * blockDim.x + threadIdx.x;
    if (i >= N * LATENT) return;
    int n = i >> 5, j = i & 31;
    const float* hr = h + (long)n * 64;
    float acc = bmu[j];
#pragma unroll
    for (int k = 0; k < 64; k++) acc += hr[k] * Wmu[k * LATENT + j];
    z[i] = acc;
}

// ---------------- recon = z @ W_dec + b_dec  (32 -> 128) ----------------
__global__ void k_dec(const float* __restrict__ z, const float* __restrict__ W,
                      const float* __restrict__ b, float* __restrict__ out, int N) {
    int i = blockIdx.x * blockDim.x + threadIdx.x;
    if (i >= N * IN_DIM) return;
    int n = i >> 7, j = i & 127;
    const float* zr = z + (long)n * LATENT;
    float acc = b[j];
#pragma unroll
    for (int k = 0; k < LATENT; k++) acc += zr[k] * W[k * IN_DIM + j];
    out[i] = acc;
}

// ---------------- link: half-wave (32 lanes) per original edge ----------------
__global__ void k_link(const float* __restrict__ z, const int* __restrict__ ei,
                       const float* __restrict__ w, float* __restrict__ link, int E0) {
    int t = blockIdx.x * blockDim.x + threadIdx.x;
    int e = t >> 5;
    int c = t & 31;
    if (e >= E0) return;
    int s = ei[e], d = ei[E0 + e];
    float v = z[(long)s * LATENT + c] * z[(long)d * LATENT + c] * w[c];
    for (int off = 16; off; off >>= 1) v += __shfl_xor(v, off);
    if (c == 0) link[e] = v;
}

// ---------------- global add pool: exploit sorted batch ----------------
#define NPB_POOL 1024
__global__ void k_pool(const float* __restrict__ z, const int* __restrict__ batch,
                       float* __restrict__ gemb, int N) {
    int t = threadIdx.x;
    int j = t & 31;
    int r = t >> 5;  // 0..7
    int start = blockIdx.x * NPB_POOL;
    int end = min(start + NPB_POOL, N);

    float acc = 0.f;
    int cur_g = -1;
    for (int n = start + r; n < end; n += 8) {
        int g = batch[n];
        if (g != cur_g) {
            if (cur_g >= 0) atomicAdd(&gemb[cur_g * LATENT + j], acc);
            acc = 0.f;
            cur_g = g;
        }
        acc += z[(size_t)n * LATENT + j];
    }
    if (cur_g >= 0) atomicAdd(&gemb[cur_g * LATENT + j], acc);
}

// ---------------- classifier ----------------
__global__ void k_cls(const float* __restrict__ g, const float* __restrict__ W,
                      const float* __restrict__ b, float* __restrict__ out) {
    int i = blockIdx.x * blockDim.x + threadIdx.x;
    if (i >= NUM_GRAPHS * NUM_CLASSES) return;
    int gi = i / NUM_CLASSES, j = i % NUM_CLASSES;
    float acc = b[j];
#pragma unroll
    for (int k = 0; k < LATENT; k++) acc += g[gi * LATENT + k] * W[k * NUM_CLASSES + j];
    out[i] = acc;
}

extern "C" void kernel_launch(void* const* d_in, const int* in_sizes, int n_in, void* d_out,
                              int out_size, void* d_ws, size_t ws_size, hipStream_t stream) {
    const float* x = (const float*)d_in[0];
    const int* ei = (const int*)d_in[1];
    const float* ea = (const float*)d_in[2];
    const int* batch = (const int*)d_in[3];
    const float* Wl0 = (const float*)d_in[4];
    const float* Wr0 = (const float*)d_in[5];
    const float* We0 = (const float*)d_in[6];
    const float* att0 = (const float*)d_in[7];
    const float* b0 = (const float*)d_in[8];
    const float* Wl1 = (const float*)d_in[9];
    const float* Wr1 = (const float*)d_in[10];
    const float* We1 = (const float*)d_in[11];
    const float* att1 = (const float*)d_in[12];
    const float* b1 = (const float*)d_in[13];
    const float* Wmu = (const float*)d_in[14];
    const float* bmu = (const float*)d_in[15];
    const float* Wdec = (const float*)d_in[16];
    const float* bdec = (const float*)d_in[17];
    const float* Wcls = (const float*)d_in[18];
    const float* bcls = (const float*)d_in[19];
    const float* weight = (const float*)d_in[20];

    const int N = in_sizes[0] / IN_DIM;  // 50000
    const int E0 = in_sizes[1] / 2;      // 400000

    // workspace layout (16B-aligned chunks)
    float* ws = (float*)d_ws;
    size_t o = 0;
    float* A = ws + o; o += (size_t)N * HC;       // xl  [N,256]
    float* B = ws + o; o += (size_t)N * HC;       // xr  [N,256]
    float4* csr_a = (float4*)(ws + o); o += (size_t)E0 * 4;
    int* csr_src = (int*)(ws + o); o += E0;
    int* deg = (int*)(ws + o); o += N;
    int* coff = (int*)(ws + o); o += N;
    int* cur = (int*)(ws + o); o += N;
    int* bsum = (int*)(ws + o); o += 256;
    float* G = ws + o; o += (size_t)N * HIDDEN;   // layer output h
    float* easum = ws + o; o += 16;
    float* gemb = ws + o; o += NUM_GRAPHS * LATENT;

    // output layout: z | recon | link | logits
    float* out = (float*)d_out;
    float* z_out = out;
    float* recon_out = out + (size_t)N * LATENT;
    float* link_out = recon_out + (size_t)N * IN_DIM;
    float* logits_out = link_out + (size_t)E0;

    const int TB = 256;
    const int nb = (N + 255) / 256;                 // scan blocks (<=256)
    const int nodeBlocks = (N * 64 + TB - 1) / TB;  // one wave per node
    const float invE = 1.f / (float)E0;
    const int gemmBlocks = (N + 15) / 16;

    // ---- init + CSR build (shared by both layers) ----
    hipMemsetAsync(deg, 0, (size_t)N * sizeof(int), stream);
    hipMemsetAsync(easum, 0, 16 * sizeof(float), stream);
    hipMemsetAsync(gemb, 0, NUM_GRAPHS * LATENT * sizeof(float), stream);
    k_easum<<<256, TB, 0, stream>>>(ea, E0, easum);
    k_hist<<<(E0 + TB - 1) / TB, TB, 0, stream>>>(ei, deg, E0);
    k_scan1<<<nb, 256, 0, stream>>>(deg, coff, bsum, N);
    k_scan2<<<1, 256, 0, stream>>>(bsum, nb);
    k_scan3<<<nb, 256, 0, stream>>>(coff, bsum, cur, N);
    k_scatter<<<(E0 + TB - 1) / TB, TB, 0, stream>>>(ei, ea, cur, csr_src, csr_a, E0);

    // ---- layer 0 ----
    k_gemm<IN_DIM><<<gemmBlocks, TB, 0, stream>>>(x, Wl0, Wr0, A, B, N);
    k_gat<<<nodeBlocks, TB, 0, stream>>>(A, B, csr_src, csr_a, coff, deg, easum, invE, We0,
                                         att0, b0, G, N);

    // ---- layer 1 ----
    k_gemm<HIDDEN><<<gemmBlocks, TB, 0, stream>>>(G, Wl1, Wr1, A, B, N);
    k_gat<<<nodeBlocks, TB, 0, stream>>>(A, B, csr_src, csr_a, coff, deg, easum, invE, We1,
                                         att1, b1, G, N);

    // ---- heads ----
    k_mu<<<(N * LATENT + TB - 1) / TB, TB, 0, stream>>>(G, Wmu, bmu, z_out, N);
    k_dec<<<(N * IN_DIM + TB - 1) / TB, TB, 0, stream>>>(z_out, Wdec, bdec, recon_out, N);
    k_link<<<(E0 * 32 + TB - 1) / TB, TB, 0, stream>>>(z_out, ei, weight, link_out, E0);
    k_pool<<<(N + NPB_POOL - 1) / NPB_POOL, TB, 0, stream>>>(z_out, batch, gemb, N);
    k_cls<<<(NUM_GRAPHS * NUM_CLASSES + TB - 1) / TB, TB, 0, stream>>>(gemb, Wcls, bcls,
                                                                       logits_out);
}

// Round 9
// 652.609 us; speedup vs baseline: 1.1218x; 1.1218x over previous
//
#include <hip/hip_runtime.h>
#include <math.h>

#define HIDDEN 64
#define LATENT 32
#define HEADS 4
#define IN_DIM 128
#define NUM_CLASSES 10
#define NUM_GRAPHS 64
#define NEG_SLOPE 0.2f
#define HC 256  // HEADS*HIDDEN

// ---------------- utility ----------------
__global__ void k_easum(const float* __restrict__ ea, int E, float* __restrict__ ea_sum) {
    float s0 = 0.f, s1 = 0.f, s2 = 0.f;
    for (int e = blockIdx.x * blockDim.x + threadIdx.x; e < E; e += gridDim.x * blockDim.x) {
        s0 += ea[e * 3 + 0];
        s1 += ea[e * 3 + 1];
        s2 += ea[e * 3 + 2];
    }
    for (int off = 32; off; off >>= 1) {
        s0 += __shfl_xor(s0, off);
        s1 += __shfl_xor(s1, off);
        s2 += __shfl_xor(s2, off);
    }
    if ((threadIdx.x & 63) == 0) {
        atomicAdd(&ea_sum[0], s0);
        atomicAdd(&ea_sum[1], s1);
        atomicAdd(&ea_sum[2], s2);
    }
}

// ---------------- CSR build ----------------
__global__ void k_hist(const int* __restrict__ ei, int* __restrict__ deg, int E0) {
    int e = blockIdx.x * blockDim.x + threadIdx.x;
    if (e < E0) atomicAdd(&deg[ei[E0 + e]], 1);
}

__global__ void k_scan1(const int* __restrict__ deg, int* __restrict__ off,
                        int* __restrict__ bsum, int N) {
    __shared__ int sh[256];
    int t = threadIdx.x, i = blockIdx.x * 256 + t;
    int v = (i < N) ? deg[i] : 0;
    sh[t] = v;
    __syncthreads();
    for (int d = 1; d < 256; d <<= 1) {
        int x = (t >= d) ? sh[t - d] : 0;
        __syncthreads();
        sh[t] += x;
        __syncthreads();
    }
    if (i < N) off[i] = sh[t] - v;  // exclusive
    if (t == 255) bsum[blockIdx.x] = sh[255];
}

__global__ void k_scan2(int* __restrict__ bsum, int nb) {
    __shared__ int sh[256];
    int t = threadIdx.x;
    int v = (t < nb) ? bsum[t] : 0;
    sh[t] = v;
    __syncthreads();
    for (int d = 1; d < 256; d <<= 1) {
        int x = (t >= d) ? sh[t - d] : 0;
        __syncthreads();
        sh[t] += x;
        __syncthreads();
    }
    if (t < nb) bsum[t] = sh[t] - v;  // exclusive block offsets
}

__global__ void k_scan3(int* __restrict__ off, const int* __restrict__ bsum,
                        int* __restrict__ cur, int N) {
    int i = blockIdx.x * 256 + threadIdx.x;
    if (i >= N) return;
    int o = off[i] + bsum[blockIdx.x];
    off[i] = o;
    cur[i] = o;
}

__global__ void k_scatter(const int* __restrict__ ei, const float* __restrict__ ea,
                          int* __restrict__ cur, int* __restrict__ csr_src,
                          float4* __restrict__ csr_a, int E0) {
    int e = blockIdx.x * blockDim.x + threadIdx.x;
    if (e >= E0) return;
    int dst = ei[E0 + e];
    int pos = atomicAdd(&cur[dst], 1);
    csr_src[pos] = ei[e];
    csr_a[pos] = make_float4(ea[e * 3], ea[e * 3 + 1], ea[e * 3 + 2], 0.f);
}

// ---------------- fused dual GEMM: xl = X@Wl, xr = X@Wr in ONE dispatch ----------------
// R6/R7 winner (95 us L0): NPB=16 nodes/block, X staged TRANSPOSED in LDS [k][node]
// (stride 20: staging 2-way alias = free; reads are ds_read_b128 broadcasts).
// Per k: 2 coalesced global W loads + 4 LDS reads + 32 FMAs.
template <int K>
__global__ void k_gemm(const float* __restrict__ X, const float* __restrict__ Wl,
                       const float* __restrict__ Wr, float* __restrict__ xl,
                       float* __restrict__ xr, int N) {
    constexpr int NPB = 16;
    constexpr int LDR = 20;
    __shared__ float sxt[K * LDR];

    const int t = threadIdx.x;
    const int M0 = blockIdx.x * NPB;

    constexpr int NV4 = NPB * K / 4;
#pragma unroll
    for (int idx = t; idx < NV4; idx += 256) {
        int node = idx & 15;
        int kq = idx >> 4;
        float4 v = make_float4(0.f, 0.f, 0.f, 0.f);
        if (M0 + node < N) v = ((const float4*)(X + (size_t)(M0 + node) * K))[kq];
        int k = kq * 4;
        sxt[(k + 0) * LDR + node] = v.x;
        sxt[(k + 1) * LDR + node] = v.y;
        sxt[(k + 2) * LDR + node] = v.z;
        sxt[(k + 3) * LDR + node] = v.w;
    }
    __syncthreads();

    float accl[NPB], accr[NPB];
#pragma unroll
    for (int n = 0; n < NPB; n++) { accl[n] = 0.f; accr[n] = 0.f; }

    const float* wlp = Wl + t;
    const float* wrp = Wr + t;
#pragma unroll 4
    for (int k = 0; k < K; k++) {
        float wl = wlp[(size_t)k * HC];
        float wr = wrp[(size_t)k * HC];
        float a[NPB];
        *(float4*)&a[0] = *(const float4*)&sxt[k * LDR + 0];
        *(float4*)&a[4] = *(const float4*)&sxt[k * LDR + 4];
        *(float4*)&a[8] = *(const float4*)&sxt[k * LDR + 8];
        *(float4*)&a[12] = *(const float4*)&sxt[k * LDR + 12];
#pragma unroll
        for (int n = 0; n < NPB; n++) {
            accl[n] += a[n] * wl;
            accr[n] += a[n] * wr;
        }
    }

#pragma unroll
    for (int n = 0; n < NPB; n++) {
        int gn = M0 + n;
        if (gn < N) {
            xl[(size_t)gn * HC + t] = accl[n];
            xr[(size_t)gn * HC + t] = accr[n];
        }
    }
}

// ---------------- fused GATv2 layer: wave per node, online softmax ----------------
// lane L holds cols 4L..4L+3 of the 256-wide row; head h = L>>4.
// Wave-cooperative CSR staging: lane L loads csr_src/csr_a[base+L] once (coalesced);
// per-edge index/attrs come from __shfl. Gather for edge i+1 is issued before
// computing edge i (1-deep pipeline) -- indices are known upfront, so gathers overlap
// compute instead of serializing behind a dependent index load.
__global__ void k_gat(const float* __restrict__ xl, const float* __restrict__ xr,
                      const int* __restrict__ csr_src, const float4* __restrict__ csr_a,
                      const int* __restrict__ off, const int* __restrict__ deg,
                      const float* __restrict__ easum, float invE,
                      const float* __restrict__ We, const float* __restrict__ att,
                      const float* __restrict__ bias, float* __restrict__ out, int N) {
    int wid = (blockIdx.x * blockDim.x + threadIdx.x) >> 6;
    int L = threadIdx.x & 63;
    if (wid >= N) return;
    int n = wid;

    float4 xr4 = ((const float4*)(xr + (size_t)n * HC))[L];
    float4 w0 = ((const float4*)We)[L];
    float4 w1 = ((const float4*)(We + HC))[L];
    float4 w2 = ((const float4*)(We + 2 * HC))[L];
    float4 at = ((const float4*)att)[L];

    float m = -INFINITY, d = 0.f;
    float acc0 = 0.f, acc1 = 0.f, acc2 = 0.f, acc3 = 0.f;
    int base = off[n], cnt = deg[n];

    // self-loop first (mean edge attr)
    {
        float a0 = easum[0] * invE, a1 = easum[1] * invE, a2 = easum[2] * invE;
        float4 xs = ((const float4*)(xl + (size_t)n * HC))[L];
        float s0 = xs.x + xr4.x + (a0 * w0.x + a1 * w1.x + a2 * w2.x);
        float s1 = xs.y + xr4.y + (a0 * w0.y + a1 * w1.y + a2 * w2.y);
        float s2 = xs.z + xr4.z + (a0 * w0.z + a1 * w1.z + a2 * w2.z);
        float s3 = xs.w + xr4.w + (a0 * w0.w + a1 * w1.w + a2 * w2.w);
        s0 = (s0 > 0.f) ? s0 : NEG_SLOPE * s0;
        s1 = (s1 > 0.f) ? s1 : NEG_SLOPE * s1;
        s2 = (s2 > 0.f) ? s2 : NEG_SLOPE * s2;
        s3 = (s3 > 0.f) ? s3 : NEG_SLOPE * s3;
        float p = s0 * at.x + s1 * at.y + s2 * at.z + s3 * at.w;
        p += __shfl_xor(p, 1);
        p += __shfl_xor(p, 2);
        p += __shfl_xor(p, 4);
        p += __shfl_xor(p, 8);
        float mn = fmaxf(m, p);
        float sc = __expf(m - mn);
        float ex = __expf(p - mn);
        d = d * sc + ex;
        acc0 = acc0 * sc + ex * xs.x;
        acc1 = acc1 * sc + ex * xs.y;
        acc2 = acc2 * sc + ex * xs.z;
        acc3 = acc3 * sc + ex * xs.w;
        m = mn;
    }

    for (int c0 = 0; c0 < cnt; c0 += 64) {
        int mm = cnt - c0;
        if (mm > 64) mm = 64;
        // wave-cooperative staging of up to 64 edges
        int msrc = 0;
        float4 ma = make_float4(0.f, 0.f, 0.f, 0.f);
        if (L < mm) {
            msrc = csr_src[base + c0 + L];
            ma = csr_a[base + c0 + L];
        }
        // prime the gather pipeline
        int src0 = __shfl(msrc, 0);
        float4 xs_next = ((const float4*)(xl + (size_t)src0 * HC))[L];
        for (int i = 0; i < mm; i++) {
            float4 xs = xs_next;
            if (i + 1 < mm) {
                int srcn = __shfl(msrc, i + 1);
                xs_next = ((const float4*)(xl + (size_t)srcn * HC))[L];
            }
            float a0 = __shfl(ma.x, i);
            float a1 = __shfl(ma.y, i);
            float a2 = __shfl(ma.z, i);
            float s0 = xs.x + xr4.x + (a0 * w0.x + a1 * w1.x + a2 * w2.x);
            float s1 = xs.y + xr4.y + (a0 * w0.y + a1 * w1.y + a2 * w2.y);
            float s2 = xs.z + xr4.z + (a0 * w0.z + a1 * w1.z + a2 * w2.z);
            float s3 = xs.w + xr4.w + (a0 * w0.w + a1 * w1.w + a2 * w2.w);
            s0 = (s0 > 0.f) ? s0 : NEG_SLOPE * s0;
            s1 = (s1 > 0.f) ? s1 : NEG_SLOPE * s1;
            s2 = (s2 > 0.f) ? s2 : NEG_SLOPE * s2;
            s3 = (s3 > 0.f) ? s3 : NEG_SLOPE * s3;
            float p = s0 * at.x + s1 * at.y + s2 * at.z + s3 * at.w;
            p += __shfl_xor(p, 1);
            p += __shfl_xor(p, 2);
            p += __shfl_xor(p, 4);
            p += __shfl_xor(p, 8);
            float mn = fmaxf(m, p);
            float sc = __expf(m - mn);
            float ex = __expf(p - mn);
            d = d * sc + ex;
            acc0 = acc0 * sc + ex * xs.x;
            acc1 = acc1 * sc + ex * xs.y;
            acc2 = acc2 * sc + ex * xs.z;
            acc3 = acc3 * sc + ex * xs.w;
            m = mn;
        }
    }

    float inv_d = 1.f / d;
    float v0 = acc0 * inv_d, v1 = acc1 * inv_d, v2 = acc2 * inv_d, v3 = acc3 * inv_d;
    // head-mean: sum over lanes L^16, L^32
    v0 += __shfl_xor(v0, 16); v1 += __shfl_xor(v1, 16);
    v2 += __shfl_xor(v2, 16); v3 += __shfl_xor(v3, 16);
    v0 += __shfl_xor(v0, 32); v1 += __shfl_xor(v1, 32);
    v2 += __shfl_xor(v2, 32); v3 += __shfl_xor(v3, 32);
    if (L < 16) {
        float4 bx = ((const float4*)bias)[L];
        float4 o;
        o.x = fmaxf(0.25f * v0 + bx.x, 0.f);
        o.y = fmaxf(0.25f * v1 + bx.y, 0.f);
        o.z = fmaxf(0.25f * v2 + bx.z, 0.f);
        o.w = fmaxf(0.25f * v3 + bx.w, 0.f);
        ((float4*)(out + (size_t)n * HIDDEN))[L] = o;
    }
}

// ---------------- z = h @ W_mu + b_mu  (64 -> 32) ----------------
__global__ void k_mu(const float* __restrict__ h, const float* __restrict__ Wmu,
                     const float* __restrict__ bmu, float* __restrict__ z, int N) {
    int i = blockIdx.x * blockDim.x + threadIdx.x;
    if (i >= N * LATENT) return;
    int n = i >> 5, j = i & 31;
    const float* hr = h + (long)n * 64;
    float acc = bmu[j];
#pragma unroll
    for (int k = 0; k < 64; k++) acc += hr[k] * Wmu[k * LATENT + j];
    z[i] = acc;
}

// ---------------- recon = z @ W_dec + b_dec  (32 -> 128) ----------------
__global__ void k_dec(const float* __restrict__ z, const float* __restrict__ W,
                      const float* __restrict__ b, float* __restrict__ out, int N) {
    int i = blockIdx.x * blockDim.x + threadIdx.x;
    if (i >= N * IN_DIM) return;
    int n = i >> 7, j = i & 127;
    const float* zr = z + (long)n * LATENT;
    float acc = b[j];
#pragma unroll
    for (int k = 0; k < LATENT; k++) acc += zr[k] * W[k * IN_DIM + j];
    out[i] = acc;
}

// ---------------- link: half-wave (32 lanes) per original edge ----------------
__global__ void k_link(const float* __restrict__ z, const int* __restrict__ ei,
                       const float* __restrict__ w, float* __restrict__ link, int E0) {
    int t = blockIdx.x * blockDim.x + threadIdx.x;
    int e = t >> 5;
    int c = t & 31;
    if (e >= E0) return;
    int s = ei[e], d = ei[E0 + e];
    float v = z[(long)s * LATENT + c] * z[(long)d * LATENT + c] * w[c];
    for (int off = 16; off; off >>= 1) v += __shfl_xor(v, off);
    if (c == 0) link[e] = v;
}

// ---------------- global add pool: exploit sorted batch ----------------
#define NPB_POOL 1024
__global__ void k_pool(const float* __restrict__ z, const int* __restrict__ batch,
                       float* __restrict__ gemb, int N) {
    int t = threadIdx.x;
    int j = t & 31;
    int r = t >> 5;  // 0..7
    int start = blockIdx.x * NPB_POOL;
    int end = min(start + NPB_POOL, N);

    float acc = 0.f;
    int cur_g = -1;
    for (int n = start + r; n < end; n += 8) {
        int g = batch[n];
        if (g != cur_g) {
            if (cur_g >= 0) atomicAdd(&gemb[cur_g * LATENT + j], acc);
            acc = 0.f;
            cur_g = g;
        }
        acc += z[(size_t)n * LATENT + j];
    }
    if (cur_g >= 0) atomicAdd(&gemb[cur_g * LATENT + j], acc);
}

// ---------------- classifier ----------------
__global__ void k_cls(const float* __restrict__ g, const float* __restrict__ W,
                      const float* __restrict__ b, float* __restrict__ out) {
    int i = blockIdx.x * blockDim.x + threadIdx.x;
    if (i >= NUM_GRAPHS * NUM_CLASSES) return;
    int gi = i / NUM_CLASSES, j = i % NUM_CLASSES;
    float acc = b[j];
#pragma unroll
    for (int k = 0; k < LATENT; k++) acc += g[gi * LATENT + k] * W[k * NUM_CLASSES + j];
    out[i] = acc;
}

extern "C" void kernel_launch(void* const* d_in, const int* in_sizes, int n_in, void* d_out,
                              int out_size, void* d_ws, size_t ws_size, hipStream_t stream) {
    const float* x = (const float*)d_in[0];
    const int* ei = (const int*)d_in[1];
    const float* ea = (const float*)d_in[2];
    const int* batch = (const int*)d_in[3];
    const float* Wl0 = (const float*)d_in[4];
    const float* Wr0 = (const float*)d_in[5];
    const float* We0 = (const float*)d_in[6];
    const float* att0 = (const float*)d_in[7];
    const float* b0 = (const float*)d_in[8];
    const float* Wl1 = (const float*)d_in[9];
    const float* Wr1 = (const float*)d_in[10];
    const float* We1 = (const float*)d_in[11];
    const float* att1 = (const float*)d_in[12];
    const float* b1 = (const float*)d_in[13];
    const float* Wmu = (const float*)d_in[14];
    const float* bmu = (const float*)d_in[15];
    const float* Wdec = (const float*)d_in[16];
    const float* bdec = (const float*)d_in[17];
    const float* Wcls = (const float*)d_in[18];
    const float* bcls = (const float*)d_in[19];
    const float* weight = (const float*)d_in[20];

    const int N = in_sizes[0] / IN_DIM;  // 50000
    const int E0 = in_sizes[1] / 2;      // 400000

    // workspace layout (16B-aligned chunks)
    float* ws = (float*)d_ws;
    size_t o = 0;
    float* A = ws + o; o += (size_t)N * HC;       // xl  [N,256]
    float* B = ws + o; o += (size_t)N * HC;       // xr  [N,256]
    float4* csr_a = (float4*)(ws + o); o += (size_t)E0 * 4;
    int* csr_src = (int*)(ws + o); o += E0;
    int* deg = (int*)(ws + o); o += N;
    int* coff = (int*)(ws + o); o += N;
    int* cur = (int*)(ws + o); o += N;
    int* bsum = (int*)(ws + o); o += 256;
    float* G = ws + o; o += (size_t)N * HIDDEN;   // layer output h
    float* easum = ws + o; o += 16;
    float* gemb = ws + o; o += NUM_GRAPHS * LATENT;

    // output layout: z | recon | link | logits
    float* out = (float*)d_out;
    float* z_out = out;
    float* recon_out = out + (size_t)N * LATENT;
    float* link_out = recon_out + (size_t)N * IN_DIM;
    float* logits_out = link_out + (size_t)E0;

    const int TB = 256;
    const int nb = (N + 255) / 256;                 // scan blocks (<=256)
    const int nodeBlocks = (N * 64 + TB - 1) / TB;  // one wave per node
    const float invE = 1.f / (float)E0;
    const int gemmBlocks = (N + 15) / 16;

    // ---- init + CSR build (shared by both layers) ----
    hipMemsetAsync(deg, 0, (size_t)N * sizeof(int), stream);
    hipMemsetAsync(easum, 0, 16 * sizeof(float), stream);
    hipMemsetAsync(gemb, 0, NUM_GRAPHS * LATENT * sizeof(float), stream);
    k_easum<<<256, TB, 0, stream>>>(ea, E0, easum);
    k_hist<<<(E0 + TB - 1) / TB, TB, 0, stream>>>(ei, deg, E0);
    k_scan1<<<nb, 256, 0, stream>>>(deg, coff, bsum, N);
    k_scan2<<<1, 256, 0, stream>>>(bsum, nb);
    k_scan3<<<nb, 256, 0, stream>>>(coff, bsum, cur, N);
    k_scatter<<<(E0 + TB - 1) / TB, TB, 0, stream>>>(ei, ea, cur, csr_src, csr_a, E0);

    // ---- layer 0 ----
    k_gemm<IN_DIM><<<gemmBlocks, TB, 0, stream>>>(x, Wl0, Wr0, A, B, N);
    k_gat<<<nodeBlocks, TB, 0, stream>>>(A, B, csr_src, csr_a, coff, deg, easum, invE, We0,
                                         att0, b0, G, N);

    // ---- layer 1 ----
    k_gemm<HIDDEN><<<gemmBlocks, TB, 0, stream>>>(G, Wl1, Wr1, A, B, N);
    k_gat<<<nodeBlocks, TB, 0, stream>>>(A, B, csr_src, csr_a, coff, deg, easum, invE, We1,
                                         att1, b1, G, N);

    // ---- heads ----
    k_mu<<<(N * LATENT + TB - 1) / TB, TB, 0, stream>>>(G, Wmu, bmu, z_out, N);
    k_dec<<<(N * IN_DIM + TB - 1) / TB, TB, 0, stream>>>(z_out, Wdec, bdec, recon_out, N);
    k_link<<<(E0 * 32 + TB - 1) / TB, TB, 0, stream>>>(z_out, ei, weight, link_out, E0);
    k_pool<<<(N + NPB_POOL - 1) / NPB_POOL, TB, 0, stream>>>(z_out, batch, gemb, N);
    k_cls<<<(NUM_GRAPHS * NUM_CLASSES + TB - 1) / TB, TB, 0, stream>>>(gemb, Wcls, bcls,
                                                                       logits_out);
}